// Round 2
// baseline (324.774 us; speedup 1.0000x reference)
//
#include <hip/hip_runtime.h>
#include <hip/hip_bf16.h>
#include <math.h>
#include <stdint.h>

// Problem constants (B=2, S=2048 -> T=4096 tokens)
#define TOKENS 4096
#define HDIM   768
#define FFDIM  1536
#define NEXP   8
#define GEMM_GRID 1024  // 128 slots per bucket; id%8 = bucket -> XCD affinity
#define SLOTS (GEMM_GRID / 8)

typedef __attribute__((ext_vector_type(8))) short bf16x8;   // 8 bf16 = 4 VGPRs
typedef __attribute__((ext_vector_type(4))) float f32x4;    // MFMA accumulator

// round-to-nearest-even f32 -> bf16 (bit pattern)
__device__ __forceinline__ unsigned short f2bf(float f) {
    union { float f; uint32_t u; } c; c.f = f;
    uint32_t u = c.u;
    uint32_t r = (u + 0x7FFFu + ((u >> 16) & 1u)) >> 16;
    return (unsigned short)r;
}

// async global->LDS, 16B per lane; LDS dest is wave-uniform base + lane*16
__device__ __forceinline__ void gload_lds16(const void* g, void* l) {
    __builtin_amdgcn_global_load_lds(
        (const __attribute__((address_space(1))) void*)g,
        (__attribute__((address_space(3))) void*)l, 16, 0, 0);
}

// ---------------------------------------------------------------------------
// both weight casts in one dispatch; n4 = float4 count of EACH tensor.
// Also zeroes the 8 routing counters (this kernel is first in stream, so the
// counters are clean before gating's atomicAdd slot assignment).
__global__ void cast_bf16_2(const float* __restrict__ s1, unsigned short* __restrict__ d1,
                            const float* __restrict__ s2, unsigned short* __restrict__ d2,
                            int n4, int* __restrict__ counts) {
    if (blockIdx.x == 0 && threadIdx.x < NEXP) counts[threadIdx.x] = 0;
    int stride = gridDim.x * blockDim.x;
    for (int i = blockIdx.x * blockDim.x + threadIdx.x; i < 2 * n4; i += stride) {
        const float4* s = (i < n4) ? (const float4*)s1 : (const float4*)s2;
        ushort4* d = (i < n4) ? (ushort4*)d1 : (ushort4*)d2;
        int j = (i < n4) ? i : i - n4;
        float4 v = s[j];
        ushort4 o;
        o.x = f2bf(v.x); o.y = f2bf(v.y); o.z = f2bf(v.z); o.w = f2bf(v.w);
        d[j] = o;
    }
}

// ---------------------------------------------------------------------------
// Gating: one wave per token (4 tokens / 256-thread block). fp32 logits
// (checked output!), top-2 softmax. Fused: bf16 cast of x, zeroing of outp
// (must precede GEMM2), and DIRECT routed-list construction via atomicAdd
// slot assignment (replaces the old single-block build_lists kernel, which
// was a serial-latency dispatch). Slot order within an expert becomes
// nondeterministic; that only permutes hmid rows and the order of the two
// f32 atomic adds per output element — GEMM2's combine was already
// order-agnostic, logits are untouched.
__global__ __launch_bounds__(256) void gating(
    const float* __restrict__ x, const float* __restrict__ gw,
    float* __restrict__ logits,
    int* __restrict__ counts, int* __restrict__ entries, float* __restrict__ gates,
    unsigned short* __restrict__ x_bf, float* __restrict__ outp)
{
    // zero outp: 786432 float4 over 1024 blocks = 3 per thread
    float4 zz = make_float4(0.f, 0.f, 0.f, 0.f);
#pragma unroll
    for (int j = 0; j < 3; j++)
        ((float4*)outp)[blockIdx.x * 768 + j * 256 + threadIdx.x] = zz;

    int t = blockIdx.x * 4 + (threadIdx.x >> 6);
    int lane = threadIdx.x & 63;
    const float4* xt = (const float4*)(x + (size_t)t * HDIM);   // 192 float4/token
    const float4* gw4 = (const float4*)gw;                      // [E][192]
    ushort4* xbt = (ushort4*)(x_bf + (size_t)t * HDIM);
    float acc[NEXP];
#pragma unroll
    for (int e = 0; e < NEXP; e++) acc[e] = 0.f;
#pragma unroll
    for (int it = 0; it < 3; it++) {
        int i = lane + it * 64;
        float4 xv = xt[i];
        ushort4 o;
        o.x = f2bf(xv.x); o.y = f2bf(xv.y); o.z = f2bf(xv.z); o.w = f2bf(xv.w);
        xbt[i] = o;
#pragma unroll
        for (int e = 0; e < NEXP; e++) {
            float4 wv = gw4[e * 192 + i];
            acc[e] += xv.x * wv.x + xv.y * wv.y + xv.z * wv.z + xv.w * wv.w;
        }
    }
#pragma unroll
    for (int e = 0; e < NEXP; e++) {
#pragma unroll
        for (int off = 32; off > 0; off >>= 1)
            acc[e] += __shfl_xor(acc[e], off);
    }
    if (lane == 0) {
        float4 l0 = make_float4(acc[0], acc[1], acc[2], acc[3]);
        float4 l1 = make_float4(acc[4], acc[5], acc[6], acc[7]);
        float4* lp = (float4*)(logits + (size_t)t * NEXP);
        lp[0] = l0; lp[1] = l1;
        int i0 = 0; float v0 = acc[0];
#pragma unroll
        for (int e = 1; e < NEXP; e++) if (acc[e] > v0) { v0 = acc[e]; i0 = e; }
        int i1 = -1; float v1 = -3.4e38f;
#pragma unroll
        for (int e = 0; e < NEXP; e++) if (e != i0 && acc[e] > v1) { v1 = acc[e]; i1 = e; }
        float g0 = 1.f / (1.f + expf(v1 - v0));   // softmax over top-2 (v0 >= v1)
        int s0 = atomicAdd(&counts[i0], 1);
        int s1 = atomicAdd(&counts[i1], 1);
        entries[i0 * TOKENS + s0] = t * 2;
        gates  [i0 * TOKENS + s0] = g0;
        entries[i1 * TOKENS + s1] = t * 2 + 1;
        gates  [i1 * TOKENS + s1] = 1.f - g0;
    }
}

// ---------------------------------------------------------------------------
// Routed GEMM, 128xTN tile, BK=64, single-buffer 2-barrier K-loop.
// r10 structure: ONE ITEM PER BLOCK, ALL ITEMS CONCURRENT.
//   - grid 1024 = 128 slots/bucket > worst typical fill (~96-108), so no
//     block runs a serial second item (the ~48-block 2x-span tail that made
//     OccupancyPercent average ~half of peak in r0/r1 is gone). Backstop
//     stride loop handles pathological imbalance.
//   - 32KB LDS + __launch_bounds__(256,4) -> 4 blocks/CU -> 1024 resident
//     at t=0: every item starts immediately.
//   - work/fill/bases tables are gone: geometry derived from counts[8]
//     (rts = ceil(c/128), nfill = rts*NCT, ct = p/rts, r = p%rts, ebase =
//     prefix of counts). bucket == expert (XCD-affine under round-robin).
// LDS rows 128B (8x16B segs), XOR swizzle seg^(row&7): ds_read_b128
// bank-uniform, 0 conflicts (verified r6). 4 waves in 2x2.
//   IS_FC:  A = x_bf gathered via entry list (row = entry>>1), out = gelu ->
//           hmid[ebase+slot][ND] (slot-compacted, so GEMM2 reads it dense)
//   !IS_FC: A = hmid[ebase+row] contiguous, out = atomicAdd(gate * acc)
template<int KD, int ND, int TN, int NCTP, bool IS_FC>
__global__ __launch_bounds__(256, 4) void moe_gemm(
    const unsigned short* __restrict__ Asrc,
    const unsigned short* __restrict__ Bsrc,    // [E][ND][KD] (B^T form)
    const int* __restrict__ counts,
    const int* __restrict__ entries,
    const float* __restrict__ gates,
    unsigned short* __restrict__ hmid,
    float* __restrict__ outp)
{
    constexpr int AJ = TN / 32;        // col frags per wave (4 or 2)
    constexpr int CB = TN / 32;        // B staging calls per thread (4 or 2)
    int bkt  = blockIdx.x & 7;         // bucket == expert
    int slot = blockIdx.x >> 3;        // 0..SLOTS-1

    // per-expert geometry from the 8 routing counters (uniform scalar work)
    int cs[NEXP];
#pragma unroll
    for (int e = 0; e < NEXP; e++) cs[e] = counts[e];
    int n_e = cs[bkt];
    int rts = (n_e + 127) >> 7;
    int nfill = rts * NCTP;
    if (slot >= nfill) return;
    int ebase = 0;
#pragma unroll
    for (int e = 0; e < NEXP; e++) if (e < bkt) ebase += cs[e];
    const int* lst = entries + bkt * TOKENS;

    int tid = threadIdx.x;
    int w = tid >> 6;          // wave 0..3
    int l = tid & 63;          // lane
    int sg = l & 7;
    int lr8 = l >> 3;          // row-within-8 staged by this lane
    int lo = l & 15;
    int q  = l >> 4;
    int wr = w >> 1, wc = w & 1;

    __shared__ __align__(16) unsigned short sA[128 * 64];
    __shared__ __align__(16) unsigned short sB[TN * 64];

    // fragment LDS offsets (item-independent)
    int aOff[4][2], bOff[AJ][2];
#pragma unroll
    for (int i = 0; i < 4; i++) {
        int m = wr * 64 + i * 16 + lo;
#pragma unroll
        for (int s = 0; s < 2; s++)
            aOff[i][s] = m * 64 + ((s * 4 + q) ^ (m & 7)) * 8;
    }
#pragma unroll
    for (int j = 0; j < AJ; j++) {
        int n = wc * (TN / 2) + j * 16 + lo;
#pragma unroll
        for (int s = 0; s < 2; s++)
            bOff[j][s] = n * 64 + ((s * 4 + q) ^ (n & 7)) * 8;
    }

    for (int p = slot; p < nfill; p += SLOTS) {   // backstop stride; 1 iter typical
        int ct   = p / rts;
        int r    = p - ct * rts;
        int row0 = r << 7;
        int n0 = ct * TN;

        // ---- staging addresses: rows are 128B (64 shorts), 8 segs of 16B.
        // A call covers 8 rows (64 lanes x 16B = 1KB). Global K-seg for
        // (row r, LDS seg sg) is sg ^ (r&7). Wave w stages A rows
        // [w*32, w*32+32) (4 calls) and B rows [w*(TN/4), ...) (CB calls).
        const unsigned short* Ag[4];
        int aLds[4];
#pragma unroll
        for (int c = 0; c < 4; c++) {
            int rr = w * 32 + c * 8 + lr8;       // tile row
            int gr = row0 + rr;
            int id = gr < n_e ? gr : n_e - 1;    // clamp (discarded in epilogue)
            size_t arow = IS_FC ? (size_t)(lst[id] >> 1) : (size_t)(ebase + id);
            Ag[c] = Asrc + arow * KD + (size_t)((sg ^ (rr & 7)) * 8);
            aLds[c] = (w * 32 + c * 8) * 64;     // wave-uniform chunk base
        }
        const unsigned short* Bg[CB];
        int bLds[CB];
#pragma unroll
        for (int c = 0; c < CB; c++) {
            int rr = w * (TN / 4) + c * 8 + lr8;
            Bg[c] = Bsrc + ((size_t)bkt * ND + n0 + rr) * KD + (size_t)((sg ^ (rr & 7)) * 8);
            bLds[c] = (w * (TN / 4) + c * 8) * 64;
        }

        f32x4 acc[4][AJ];
#pragma unroll
        for (int i = 0; i < 4; i++)
#pragma unroll
            for (int j = 0; j < AJ; j++) acc[i][j] = (f32x4){0.f, 0.f, 0.f, 0.f};

        for (int k0 = 0; k0 < KD; k0 += 64) {
#pragma unroll
            for (int c = 0; c < 4; c++) gload_lds16(Ag[c] + k0, sA + aLds[c]);
#pragma unroll
            for (int c = 0; c < CB; c++) gload_lds16(Bg[c] + k0, sB + bLds[c]);
            __syncthreads();                    // drains vmcnt (compiler-inserted)
#pragma unroll
            for (int s = 0; s < 2; s++) {
                bf16x8 a[4], b[AJ];
#pragma unroll
                for (int i = 0; i < 4; i++) a[i] = *(const bf16x8*)(sA + aOff[i][s]);
#pragma unroll
                for (int j = 0; j < AJ; j++) b[j] = *(const bf16x8*)(sB + bOff[j][s]);
#pragma unroll
                for (int i = 0; i < 4; i++)
#pragma unroll
                    for (int j = 0; j < AJ; j++)
                        acc[i][j] = __builtin_amdgcn_mfma_f32_16x16x32_bf16(a[i], b[j], acc[i][j], 0, 0, 0);
            }
            __syncthreads();                    // protect LDS before next staging
        }

        // ---- epilogue (D: col=lo, row=q*4+rr)
#pragma unroll
        for (int i = 0; i < 4; i++) {
            int rowB = row0 + wr * 64 + i * 16 + q * 4;
#pragma unroll
            for (int rr = 0; rr < 4; rr++) {
                int orow = rowB + rr;
                if (orow < n_e) {
                    if (IS_FC) {
                        size_t hrow = (size_t)(ebase + orow);
#pragma unroll
                        for (int j = 0; j < AJ; j++) {
                            float v = acc[i][j][rr];
                            v = 0.5f * v * (1.f + erff(v * 0.70710678118654752f));  // exact gelu
                            hmid[hrow * ND + n0 + wc * (TN / 2) + j * 16 + lo] = f2bf(v);
                        }
                    } else {
                        int token = lst[orow] >> 1;
                        float g = gates[bkt * TOKENS + orow];
#pragma unroll
                        for (int j = 0; j < AJ; j++) {
                            atomicAdd(&outp[(size_t)token * ND + n0 + wc * (TN / 2) + j * 16 + lo],
                                      acc[i][j][rr] * g);
                        }
                    }
                }
            }
        }
    }
}

// ---------------------------------------------------------------------------
extern "C" void kernel_launch(void* const* d_in, const int* in_sizes, int n_in,
                              void* d_out, int out_size, void* d_ws, size_t ws_size,
                              hipStream_t stream) {
    const float* x     = (const float*)d_in[0];   // [T, H]
    const float* gw    = (const float*)d_in[1];   // [E, H]
    const float* wfc   = (const float*)d_in[2];   // [E, FF, H]
    const float* wproj = (const float*)d_in[3];   // [E, H, FF]
    float* outp   = (float*)d_out;                       // [T*H]
    float* logits = outp + (size_t)TOKENS * HDIM;        // [T*E]

    char* ws = (char*)d_ws;
    int*   counts  = (int*)ws;                            // 8 ints
    size_t off = 256;
    int*   entries = (int*)(ws + off);                    // [E][T]
    float* gates   = (float*)(ws + off + NEXP * TOKENS * 4);
    off += 2ull * NEXP * TOKENS * 4;
    unsigned short* x_bf   = (unsigned short*)(ws + off); off += (size_t)TOKENS * HDIM * 2;
    unsigned short* wfc_bf = (unsigned short*)(ws + off); off += (size_t)NEXP * FFDIM * HDIM * 2;
    unsigned short* wpj_bf = (unsigned short*)(ws + off); off += (size_t)NEXP * HDIM * FFDIM * 2;
    unsigned short* hmid   = (unsigned short*)(ws + off);        // [2T][FF] bf16, slot-compacted

    cast_bf16_2<<<2048, 256, 0, stream>>>(wfc, wfc_bf, wproj, wpj_bf,
                                          NEXP * FFDIM * HDIM / 4, counts);
    gating<<<TOKENS / 4, 256, 0, stream>>>(x, gw, logits, counts, entries, gates,
                                           x_bf, outp);
    moe_gemm<HDIM, FFDIM, 128, FFDIM / 128, true ><<<GEMM_GRID, 256, 0, stream>>>(
        x_bf, wfc_bf, counts, entries, gates, hmid, outp);
    moe_gemm<FFDIM, HDIM, 64, HDIM / 64, false><<<GEMM_GRID, 256, 0, stream>>>(
        hmid, wpj_bf, counts, entries, gates, hmid, outp);
}

// Round 3
// 242.623 us; speedup vs baseline: 1.3386x; 1.3386x over previous
//
#include <hip/hip_runtime.h>
#include <hip/hip_bf16.h>
#include <math.h>
#include <stdint.h>

// Problem constants (B=2, S=2048 -> T=4096 tokens)
#define TOKENS 4096
#define HDIM   768
#define FFDIM  1536
#define NEXP   8
#define GEMM_GRID 1024  // 128 slots per bucket; id%8 = bucket -> XCD affinity
#define SLOTS (GEMM_GRID / 8)

typedef __attribute__((ext_vector_type(8))) short bf16x8;   // 8 bf16 = 4 VGPRs
typedef __attribute__((ext_vector_type(4))) float f32x4;    // MFMA accumulator

// round-to-nearest-even f32 -> bf16 (bit pattern)
__device__ __forceinline__ unsigned short f2bf(float f) {
    union { float f; uint32_t u; } c; c.f = f;
    uint32_t u = c.u;
    uint32_t r = (u + 0x7FFFu + ((u >> 16) & 1u)) >> 16;
    return (unsigned short)r;
}

// async global->LDS, 16B per lane; LDS dest is wave-uniform base + lane*16
__device__ __forceinline__ void gload_lds16(const void* g, void* l) {
    __builtin_amdgcn_global_load_lds(
        (const __attribute__((address_space(1))) void*)g,
        (__attribute__((address_space(3))) void*)l, 16, 0, 0);
}

// ---------------------------------------------------------------------------
// both weight casts in one dispatch; n4 = float4 count of EACH tensor
__global__ void cast_bf16_2(const float* __restrict__ s1, unsigned short* __restrict__ d1,
                            const float* __restrict__ s2, unsigned short* __restrict__ d2,
                            int n4) {
    int stride = gridDim.x * blockDim.x;
    for (int i = blockIdx.x * blockDim.x + threadIdx.x; i < 2 * n4; i += stride) {
        const float4* s = (i < n4) ? (const float4*)s1 : (const float4*)s2;
        ushort4* d = (i < n4) ? (ushort4*)d1 : (ushort4*)d2;
        int j = (i < n4) ? i : i - n4;
        float4 v = s[j];
        ushort4 o;
        o.x = f2bf(v.x); o.y = f2bf(v.y); o.z = f2bf(v.z); o.w = f2bf(v.w);
        d[j] = o;
    }
}

// ---------------------------------------------------------------------------
// Gating: one wave per token (4 tokens / 256-thread block). fp32 logits
// (checked output!), top-2 softmax, NO atomics (r2 post-mortem: 8192
// same-address atomicAdds serialized to 102 us — contended atomics are a
// latency chain). Fused: bf16 cast of x, and zeroing of outp (must precede
// GEMM2, which is stream-ordered after). Routing lists are built by the
// deterministic scan kernel below.
__global__ __launch_bounds__(256) void gating(
    const float* __restrict__ x, const float* __restrict__ gw,
    float* __restrict__ logits,
    int* __restrict__ tok_e, float* __restrict__ tok_g,
    unsigned short* __restrict__ x_bf, float* __restrict__ outp)
{
    // zero outp: 786432 float4 over 1024 blocks = 3 per thread
    float4 zz = make_float4(0.f, 0.f, 0.f, 0.f);
#pragma unroll
    for (int j = 0; j < 3; j++)
        ((float4*)outp)[blockIdx.x * 768 + j * 256 + threadIdx.x] = zz;

    int t = blockIdx.x * 4 + (threadIdx.x >> 6);
    int lane = threadIdx.x & 63;
    const float4* xt = (const float4*)(x + (size_t)t * HDIM);   // 192 float4/token
    const float4* gw4 = (const float4*)gw;                      // [E][192]
    ushort4* xbt = (ushort4*)(x_bf + (size_t)t * HDIM);
    float acc[NEXP];
#pragma unroll
    for (int e = 0; e < NEXP; e++) acc[e] = 0.f;
#pragma unroll
    for (int it = 0; it < 3; it++) {
        int i = lane + it * 64;
        float4 xv = xt[i];
        ushort4 o;
        o.x = f2bf(xv.x); o.y = f2bf(xv.y); o.z = f2bf(xv.z); o.w = f2bf(xv.w);
        xbt[i] = o;
#pragma unroll
        for (int e = 0; e < NEXP; e++) {
            float4 wv = gw4[e * 192 + i];
            acc[e] += xv.x * wv.x + xv.y * wv.y + xv.z * wv.z + xv.w * wv.w;
        }
    }
#pragma unroll
    for (int e = 0; e < NEXP; e++) {
#pragma unroll
        for (int off = 32; off > 0; off >>= 1)
            acc[e] += __shfl_xor(acc[e], off);
    }
    if (lane == 0) {
        float4 l0 = make_float4(acc[0], acc[1], acc[2], acc[3]);
        float4 l1 = make_float4(acc[4], acc[5], acc[6], acc[7]);
        float4* lp = (float4*)(logits + (size_t)t * NEXP);
        lp[0] = l0; lp[1] = l1;
        int i0 = 0; float v0 = acc[0];
#pragma unroll
        for (int e = 1; e < NEXP; e++) if (acc[e] > v0) { v0 = acc[e]; i0 = e; }
        int i1 = -1; float v1 = -3.4e38f;
#pragma unroll
        for (int e = 0; e < NEXP; e++) if (e != i0 && acc[e] > v1) { v1 = acc[e]; i1 = e; }
        float g0 = 1.f / (1.f + expf(v1 - v0));   // softmax over top-2 (v0 >= v1)
        tok_e[t * 2] = i0; tok_e[t * 2 + 1] = i1;
        tok_g[t * 2] = g0; tok_g[t * 2 + 1] = 1.f - g0;
    }
}

// ---------------------------------------------------------------------------
// Build per-expert routed lists deterministically (no global atomics).
// Single block, 1024 threads (16 waves), 8 (token,k) entries per thread.
// Per-wave __shfl_up u64 scan + 16-wave fixup. Only counts/entries/gates
// are produced — the GEMM derives all geometry (rts, nfill, ct, row0,
// ebase) arithmetically from counts[8] (r2 structure).
__global__ __launch_bounds__(1024) void build_lists(
    const int* __restrict__ tok_e, const float* __restrict__ tok_g,
    int* __restrict__ counts,
    int* __restrict__ entries, float* __restrict__ gates)
{
    __shared__ unsigned long long wlo[16], whi[16];
    int tid = threadIdx.x;
    int lane = tid & 63, wid = tid >> 6;

    int eL[8]; float gL[8];
    int4 ea = ((const int4*)tok_e)[tid * 2];
    int4 eb = ((const int4*)tok_e)[tid * 2 + 1];
    float4 ga = ((const float4*)tok_g)[tid * 2];
    float4 gb = ((const float4*)tok_g)[tid * 2 + 1];
    eL[0] = ea.x; eL[1] = ea.y; eL[2] = ea.z; eL[3] = ea.w;
    eL[4] = eb.x; eL[5] = eb.y; eL[6] = eb.z; eL[7] = eb.w;
    gL[0] = ga.x; gL[1] = ga.y; gL[2] = ga.z; gL[3] = ga.w;
    gL[4] = gb.x; gL[5] = gb.y; gL[6] = gb.z; gL[7] = gb.w;

    unsigned long long clo = 0, chi = 0;
#pragma unroll
    for (int j = 0; j < 8; j++) {
        int e = eL[j];
        unsigned long long one = 1ull << ((e & 3) * 16);
        if (e < 4) clo += one; else chi += one;
    }
    unsigned long long ilo = clo, ihi = chi;
#pragma unroll
    for (int s = 1; s < 64; s <<= 1) {
        unsigned long long t1 = __shfl_up(ilo, s);
        unsigned long long t2 = __shfl_up(ihi, s);
        if (lane >= s) { ilo += t1; ihi += t2; }
    }
    if (lane == 63) { wlo[wid] = ilo; whi[wid] = ihi; }
    __syncthreads();
    if (tid == 0) {
        unsigned long long rl = 0, rh = 0;
#pragma unroll
        for (int i = 0; i < 16; i++) {
            unsigned long long a = wlo[i], b = whi[i];
            wlo[i] = rl; whi[i] = rh;   // exclusive wave prefix
            rl += a; rh += b;
        }
#pragma unroll
        for (int e = 0; e < 4; e++) {
            counts[e]     = (int)((rl >> (e * 16)) & 0xFFFF);
            counts[e + 4] = (int)((rh >> (e * 16)) & 0xFFFF);
        }
    }
    __syncthreads();
    unsigned long long rlo = wlo[wid] + (ilo - clo);   // exclusive thread prefix
    unsigned long long rhi = whi[wid] + (ihi - chi);
#pragma unroll
    for (int j = 0; j < 8; j++) {
        int e = eL[j];
        int sh = (e & 3) * 16;
        unsigned long long one = 1ull << sh;
        int slot;
        if (e < 4) { slot = (int)((rlo >> sh) & 0xFFFF); rlo += one; }
        else       { slot = (int)((rhi >> sh) & 0xFFFF); rhi += one; }
        entries[e * TOKENS + slot] = tid * 8 + j;   // = t*2+k
        gates[e * TOKENS + slot]   = gL[j];
    }
}

// ---------------------------------------------------------------------------
// Routed GEMM, 128xTN tile, BK=64, single-buffer 2-barrier K-loop.
// ONE ITEM PER BLOCK, ALL ITEMS CONCURRENT (r2 structure, first measured
// cleanly this round):
//   - grid 1024 = 128 slots/bucket > worst typical fill (~96-108), so no
//     block runs a serial second item (r0's occupancy avg 18.4% vs 37.5%
//     resident showed duration ~= 2 spans with a near-empty second half).
//     Backstop stride loop handles pathological imbalance.
//   - 32KB LDS + __launch_bounds__(256,4) -> 4 blocks/CU -> 1024 resident
//     at t=0: every item starts immediately.
//   - geometry derived from counts[8]: rts = ceil(c/128), nfill = rts*NCTP,
//     ct = p/rts, r = p%rts, ebase = prefix of counts. bucket == expert
//     (XCD-affine under round-robin dispatch).
// LDS rows 128B (8x16B segs), XOR swizzle seg^(row&7): ds_read_b128
// bank-uniform, 0 conflicts (verified r6). 4 waves in 2x2.
//   IS_FC:  A = x_bf gathered via entry list (row = entry>>1), out = gelu ->
//           hmid[ebase+slot][ND] (slot-compacted, so GEMM2 reads it dense)
//   !IS_FC: A = hmid[ebase+row] contiguous, out = atomicAdd(gate * acc)
template<int KD, int ND, int TN, int NCTP, bool IS_FC>
__global__ __launch_bounds__(256, 4) void moe_gemm(
    const unsigned short* __restrict__ Asrc,
    const unsigned short* __restrict__ Bsrc,    // [E][ND][KD] (B^T form)
    const int* __restrict__ counts,
    const int* __restrict__ entries,
    const float* __restrict__ gates,
    unsigned short* __restrict__ hmid,
    float* __restrict__ outp)
{
    constexpr int AJ = TN / 32;        // col frags per wave (4 or 2)
    constexpr int CB = TN / 32;        // B staging calls per thread (4 or 2)
    int bkt  = blockIdx.x & 7;         // bucket == expert
    int slot = blockIdx.x >> 3;        // 0..SLOTS-1

    // per-expert geometry from the 8 routing counters (uniform scalar work)
    int cs[NEXP];
#pragma unroll
    for (int e = 0; e < NEXP; e++) cs[e] = counts[e];
    int n_e = cs[bkt];
    int rts = (n_e + 127) >> 7;
    int nfill = rts * NCTP;
    if (slot >= nfill) return;
    int ebase = 0;
#pragma unroll
    for (int e = 0; e < NEXP; e++) if (e < bkt) ebase += cs[e];
    const int* lst = entries + bkt * TOKENS;

    int tid = threadIdx.x;
    int w = tid >> 6;          // wave 0..3
    int l = tid & 63;          // lane
    int sg = l & 7;
    int lr8 = l >> 3;          // row-within-8 staged by this lane
    int lo = l & 15;
    int q  = l >> 4;
    int wr = w >> 1, wc = w & 1;

    __shared__ __align__(16) unsigned short sA[128 * 64];
    __shared__ __align__(16) unsigned short sB[TN * 64];

    // fragment LDS offsets (item-independent)
    int aOff[4][2], bOff[AJ][2];
#pragma unroll
    for (int i = 0; i < 4; i++) {
        int m = wr * 64 + i * 16 + lo;
#pragma unroll
        for (int s = 0; s < 2; s++)
            aOff[i][s] = m * 64 + ((s * 4 + q) ^ (m & 7)) * 8;
    }
#pragma unroll
    for (int j = 0; j < AJ; j++) {
        int n = wc * (TN / 2) + j * 16 + lo;
#pragma unroll
        for (int s = 0; s < 2; s++)
            bOff[j][s] = n * 64 + ((s * 4 + q) ^ (n & 7)) * 8;
    }

    for (int p = slot; p < nfill; p += SLOTS) {   // backstop stride; 1 iter typical
        int ct   = p / rts;
        int r    = p - ct * rts;
        int row0 = r << 7;
        int n0 = ct * TN;

        // ---- staging addresses: rows are 128B (64 shorts), 8 segs of 16B.
        // A call covers 8 rows (64 lanes x 16B = 1KB). Global K-seg for
        // (row r, LDS seg sg) is sg ^ (r&7). Wave w stages A rows
        // [w*32, w*32+32) (4 calls) and B rows [w*(TN/4), ...) (CB calls).
        const unsigned short* Ag[4];
        int aLds[4];
#pragma unroll
        for (int c = 0; c < 4; c++) {
            int rr = w * 32 + c * 8 + lr8;       // tile row
            int gr = row0 + rr;
            int id = gr < n_e ? gr : n_e - 1;    // clamp (discarded in epilogue)
            size_t arow = IS_FC ? (size_t)(lst[id] >> 1) : (size_t)(ebase + id);
            Ag[c] = Asrc + arow * KD + (size_t)((sg ^ (rr & 7)) * 8);
            aLds[c] = (w * 32 + c * 8) * 64;     // wave-uniform chunk base
        }
        const unsigned short* Bg[CB];
        int bLds[CB];
#pragma unroll
        for (int c = 0; c < CB; c++) {
            int rr = w * (TN / 4) + c * 8 + lr8;
            Bg[c] = Bsrc + ((size_t)bkt * ND + n0 + rr) * KD + (size_t)((sg ^ (rr & 7)) * 8);
            bLds[c] = (w * (TN / 4) + c * 8) * 64;
        }

        f32x4 acc[4][AJ];
#pragma unroll
        for (int i = 0; i < 4; i++)
#pragma unroll
            for (int j = 0; j < AJ; j++) acc[i][j] = (f32x4){0.f, 0.f, 0.f, 0.f};

        for (int k0 = 0; k0 < KD; k0 += 64) {
#pragma unroll
            for (int c = 0; c < 4; c++) gload_lds16(Ag[c] + k0, sA + aLds[c]);
#pragma unroll
            for (int c = 0; c < CB; c++) gload_lds16(Bg[c] + k0, sB + bLds[c]);
            __syncthreads();                    // drains vmcnt (compiler-inserted)
#pragma unroll
            for (int s = 0; s < 2; s++) {
                bf16x8 a[4], b[AJ];
#pragma unroll
                for (int i = 0; i < 4; i++) a[i] = *(const bf16x8*)(sA + aOff[i][s]);
#pragma unroll
                for (int j = 0; j < AJ; j++) b[j] = *(const bf16x8*)(sB + bOff[j][s]);
#pragma unroll
                for (int i = 0; i < 4; i++)
#pragma unroll
                    for (int j = 0; j < AJ; j++)
                        acc[i][j] = __builtin_amdgcn_mfma_f32_16x16x32_bf16(a[i], b[j], acc[i][j], 0, 0, 0);
            }
            __syncthreads();                    // protect LDS before next staging
        }

        // ---- epilogue (D: col=lo, row=q*4+rr)
#pragma unroll
        for (int i = 0; i < 4; i++) {
            int rowB = row0 + wr * 64 + i * 16 + q * 4;
#pragma unroll
            for (int rr = 0; rr < 4; rr++) {
                int orow = rowB + rr;
                if (orow < n_e) {
                    if (IS_FC) {
                        size_t hrow = (size_t)(ebase + orow);
#pragma unroll
                        for (int j = 0; j < AJ; j++) {
                            float v = acc[i][j][rr];
                            v = 0.5f * v * (1.f + erff(v * 0.70710678118654752f));  // exact gelu
                            hmid[hrow * ND + n0 + wc * (TN / 2) + j * 16 + lo] = f2bf(v);
                        }
                    } else {
                        int token = lst[orow] >> 1;
                        float g = gates[bkt * TOKENS + orow];
#pragma unroll
                        for (int j = 0; j < AJ; j++) {
                            atomicAdd(&outp[(size_t)token * ND + n0 + wc * (TN / 2) + j * 16 + lo],
                                      acc[i][j][rr] * g);
                        }
                    }
                }
            }
        }
    }
}

// ---------------------------------------------------------------------------
extern "C" void kernel_launch(void* const* d_in, const int* in_sizes, int n_in,
                              void* d_out, int out_size, void* d_ws, size_t ws_size,
                              hipStream_t stream) {
    const float* x     = (const float*)d_in[0];   // [T, H]
    const float* gw    = (const float*)d_in[1];   // [E, H]
    const float* wfc   = (const float*)d_in[2];   // [E, FF, H]
    const float* wproj = (const float*)d_in[3];   // [E, H, FF]
    float* outp   = (float*)d_out;                       // [T*H]
    float* logits = outp + (size_t)TOKENS * HDIM;        // [T*E]

    char* ws = (char*)d_ws;
    int*   counts  = (int*)ws;                            // 8 ints
    size_t off = 256;
    int*   entries = (int*)(ws + off);                    // [E][T]
    float* gates   = (float*)(ws + off + NEXP * TOKENS * 4);
    off += 2ull * NEXP * TOKENS * 4;
    int*   tok_e   = (int*)(ws + off);   off += (size_t)TOKENS * 2 * 4;
    float* tok_g   = (float*)(ws + off); off += (size_t)TOKENS * 2 * 4;
    unsigned short* x_bf   = (unsigned short*)(ws + off); off += (size_t)TOKENS * HDIM * 2;
    unsigned short* wfc_bf = (unsigned short*)(ws + off); off += (size_t)NEXP * FFDIM * HDIM * 2;
    unsigned short* wpj_bf = (unsigned short*)(ws + off); off += (size_t)NEXP * HDIM * FFDIM * 2;
    unsigned short* hmid   = (unsigned short*)(ws + off);        // [2T][FF] bf16, slot-compacted

    cast_bf16_2<<<2048, 256, 0, stream>>>(wfc, wfc_bf, wproj, wpj_bf,
                                          NEXP * FFDIM * HDIM / 4);
    gating<<<TOKENS / 4, 256, 0, stream>>>(x, gw, logits, tok_e, tok_g, x_bf, outp);
    build_lists<<<1, 1024, 0, stream>>>(tok_e, tok_g, counts, entries, gates);
    moe_gemm<HDIM, FFDIM, 128, FFDIM / 128, true ><<<GEMM_GRID, 256, 0, stream>>>(
        x_bf, wfc_bf, counts, entries, gates, hmid, outp);
    moe_gemm<FFDIM, HDIM, 64, HDIM / 64, false><<<GEMM_GRID, 256, 0, stream>>>(
        hmid, wpj_bf, counts, entries, gates, hmid, outp);
}

// Round 4
// 234.312 us; speedup vs baseline: 1.3861x; 1.0355x over previous
//
#include <hip/hip_runtime.h>
#include <hip/hip_bf16.h>
#include <math.h>
#include <stdint.h>

// Problem constants (B=2, S=2048 -> T=4096 tokens)
#define TOKENS 4096
#define HDIM   768
#define FFDIM  1536
#define NEXP   8
#define GEMM_GRID 1024  // 128 slots per bucket; id%8 = bucket -> XCD affinity
#define SLOTS (GEMM_GRID / 8)

typedef __attribute__((ext_vector_type(8))) short bf16x8;   // 8 bf16 = 4 VGPRs
typedef __attribute__((ext_vector_type(4))) float f32x4;    // MFMA accumulator

// round-to-nearest-even f32 -> bf16 (bit pattern)
__device__ __forceinline__ unsigned short f2bf(float f) {
    union { float f; uint32_t u; } c; c.f = f;
    uint32_t u = c.u;
    uint32_t r = (u + 0x7FFFu + ((u >> 16) & 1u)) >> 16;
    return (unsigned short)r;
}

// async global->LDS, 16B per lane; LDS dest is wave-uniform base + lane*16
__device__ __forceinline__ void gload_lds16(const void* g, void* l) {
    __builtin_amdgcn_global_load_lds(
        (const __attribute__((address_space(1))) void*)g,
        (__attribute__((address_space(3))) void*)l, 16, 0, 0);
}

// ---------------------------------------------------------------------------
// both weight casts in one dispatch; n4 = float4 count of EACH tensor
__global__ void cast_bf16_2(const float* __restrict__ s1, unsigned short* __restrict__ d1,
                            const float* __restrict__ s2, unsigned short* __restrict__ d2,
                            int n4) {
    int stride = gridDim.x * blockDim.x;
    for (int i = blockIdx.x * blockDim.x + threadIdx.x; i < 2 * n4; i += stride) {
        const float4* s = (i < n4) ? (const float4*)s1 : (const float4*)s2;
        ushort4* d = (i < n4) ? (ushort4*)d1 : (ushort4*)d2;
        int j = (i < n4) ? i : i - n4;
        float4 v = s[j];
        ushort4 o;
        o.x = f2bf(v.x); o.y = f2bf(v.y); o.z = f2bf(v.z); o.w = f2bf(v.w);
        d[j] = o;
    }
}

// ---------------------------------------------------------------------------
// Gating: one wave per token (4 tokens / 256-thread block). fp32 logits
// (checked output!), top-2 softmax, NO atomics (r2 post-mortem: 8192
// same-address atomicAdds serialized to 102 us — contended atomics are a
// latency chain). Fused: bf16 cast of x, and zeroing of outp (must precede
// GEMM2, which is stream-ordered after). Routing lists are built by the
// deterministic scan kernel below.
__global__ __launch_bounds__(256) void gating(
    const float* __restrict__ x, const float* __restrict__ gw,
    float* __restrict__ logits,
    int* __restrict__ tok_e, float* __restrict__ tok_g,
    unsigned short* __restrict__ x_bf, float* __restrict__ outp)
{
    // zero outp: 786432 float4 over 1024 blocks = 3 per thread
    float4 zz = make_float4(0.f, 0.f, 0.f, 0.f);
#pragma unroll
    for (int j = 0; j < 3; j++)
        ((float4*)outp)[blockIdx.x * 768 + j * 256 + threadIdx.x] = zz;

    int t = blockIdx.x * 4 + (threadIdx.x >> 6);
    int lane = threadIdx.x & 63;
    const float4* xt = (const float4*)(x + (size_t)t * HDIM);   // 192 float4/token
    const float4* gw4 = (const float4*)gw;                      // [E][192]
    ushort4* xbt = (ushort4*)(x_bf + (size_t)t * HDIM);
    float acc[NEXP];
#pragma unroll
    for (int e = 0; e < NEXP; e++) acc[e] = 0.f;
#pragma unroll
    for (int it = 0; it < 3; it++) {
        int i = lane + it * 64;
        float4 xv = xt[i];
        ushort4 o;
        o.x = f2bf(xv.x); o.y = f2bf(xv.y); o.z = f2bf(xv.z); o.w = f2bf(xv.w);
        xbt[i] = o;
#pragma unroll
        for (int e = 0; e < NEXP; e++) {
            float4 wv = gw4[e * 192 + i];
            acc[e] += xv.x * wv.x + xv.y * wv.y + xv.z * wv.z + xv.w * wv.w;
        }
    }
#pragma unroll
    for (int e = 0; e < NEXP; e++) {
#pragma unroll
        for (int off = 32; off > 0; off >>= 1)
            acc[e] += __shfl_xor(acc[e], off);
    }
    if (lane == 0) {
        float4 l0 = make_float4(acc[0], acc[1], acc[2], acc[3]);
        float4 l1 = make_float4(acc[4], acc[5], acc[6], acc[7]);
        float4* lp = (float4*)(logits + (size_t)t * NEXP);
        lp[0] = l0; lp[1] = l1;
        int i0 = 0; float v0 = acc[0];
#pragma unroll
        for (int e = 1; e < NEXP; e++) if (acc[e] > v0) { v0 = acc[e]; i0 = e; }
        int i1 = -1; float v1 = -3.4e38f;
#pragma unroll
        for (int e = 0; e < NEXP; e++) if (e != i0 && acc[e] > v1) { v1 = acc[e]; i1 = e; }
        float g0 = 1.f / (1.f + expf(v1 - v0));   // softmax over top-2 (v0 >= v1)
        tok_e[t * 2] = i0; tok_e[t * 2 + 1] = i1;
        tok_g[t * 2] = g0; tok_g[t * 2 + 1] = 1.f - g0;
    }
}

// ---------------------------------------------------------------------------
// Build per-expert routed lists deterministically (no global atomics).
// Single block, 1024 threads (16 waves), 8 (token,k) entries per thread.
// Per-wave __shfl_up u64 scan + 16-wave fixup. Only counts/entries/gates
// are produced — the GEMM derives all geometry (rts, nfill, ct, row0,
// ebase) arithmetically from counts[8] (r2 structure).
__global__ __launch_bounds__(1024) void build_lists(
    const int* __restrict__ tok_e, const float* __restrict__ tok_g,
    int* __restrict__ counts,
    int* __restrict__ entries, float* __restrict__ gates)
{
    __shared__ unsigned long long wlo[16], whi[16];
    int tid = threadIdx.x;
    int lane = tid & 63, wid = tid >> 6;

    int eL[8]; float gL[8];
    int4 ea = ((const int4*)tok_e)[tid * 2];
    int4 eb = ((const int4*)tok_e)[tid * 2 + 1];
    float4 ga = ((const float4*)tok_g)[tid * 2];
    float4 gb = ((const float4*)tok_g)[tid * 2 + 1];
    eL[0] = ea.x; eL[1] = ea.y; eL[2] = ea.z; eL[3] = ea.w;
    eL[4] = eb.x; eL[5] = eb.y; eL[6] = eb.z; eL[7] = eb.w;
    gL[0] = ga.x; gL[1] = ga.y; gL[2] = ga.z; gL[3] = ga.w;
    gL[4] = gb.x; gL[5] = gb.y; gL[6] = gb.z; gL[7] = gb.w;

    unsigned long long clo = 0, chi = 0;
#pragma unroll
    for (int j = 0; j < 8; j++) {
        int e = eL[j];
        unsigned long long one = 1ull << ((e & 3) * 16);
        if (e < 4) clo += one; else chi += one;
    }
    unsigned long long ilo = clo, ihi = chi;
#pragma unroll
    for (int s = 1; s < 64; s <<= 1) {
        unsigned long long t1 = __shfl_up(ilo, s);
        unsigned long long t2 = __shfl_up(ihi, s);
        if (lane >= s) { ilo += t1; ihi += t2; }
    }
    if (lane == 63) { wlo[wid] = ilo; whi[wid] = ihi; }
    __syncthreads();
    if (tid == 0) {
        unsigned long long rl = 0, rh = 0;
#pragma unroll
        for (int i = 0; i < 16; i++) {
            unsigned long long a = wlo[i], b = whi[i];
            wlo[i] = rl; whi[i] = rh;   // exclusive wave prefix
            rl += a; rh += b;
        }
#pragma unroll
        for (int e = 0; e < 4; e++) {
            counts[e]     = (int)((rl >> (e * 16)) & 0xFFFF);
            counts[e + 4] = (int)((rh >> (e * 16)) & 0xFFFF);
        }
    }
    __syncthreads();
    unsigned long long rlo = wlo[wid] + (ilo - clo);   // exclusive thread prefix
    unsigned long long rhi = whi[wid] + (ihi - chi);
#pragma unroll
    for (int j = 0; j < 8; j++) {
        int e = eL[j];
        int sh = (e & 3) * 16;
        unsigned long long one = 1ull << sh;
        int slot;
        if (e < 4) { slot = (int)((rlo >> sh) & 0xFFFF); rlo += one; }
        else       { slot = (int)((rhi >> sh) & 0xFFFF); rhi += one; }
        entries[e * TOKENS + slot] = tid * 8 + j;   // = t*2+k
        gates[e * TOKENS + slot]   = gL[j];
    }
}

// ---------------------------------------------------------------------------
// Routed GEMM, 128xTN tile, BK=64, single-buffer 2-barrier K-loop.
// ONE ITEM PER BLOCK (r2/r3 structure) with NATURAL register allocation:
// r3's __launch_bounds__(256,4) forced VGPR 120->64 and spilled ~360B/thread
// of acc/frag state to scratch (+91MB WRITE_SIZE; GEMM time = spill-write
// time). Plain __launch_bounds__(256) restores ~120 VGPR, zero spill,
// ~3 blocks/CU -> 768 of 1024 blocks resident, queue drains as blocks
// retire (~1.33x single-item span; r0's stride-loop tail was 2x).
//   - grid 1024 = 128 slots/bucket > worst typical fill (~96-108).
//   - geometry from counts[8]: rts = ceil(c/128), nfill = rts*NCTP,
//     ct = p/rts, r = p%rts, ebase = prefix of counts. bucket == expert
//     (XCD-affine under round-robin dispatch).
// LDS rows 128B (8x16B segs), XOR swizzle seg^(row&7): ds_read_b128
// bank-uniform, 0 conflicts (verified r6). 4 waves in 2x2.
//   IS_FC:  A = x_bf gathered via entry list (row = entry>>1), out = gelu ->
//           hmid[ebase+slot][ND] (slot-compacted, so GEMM2 reads it dense)
//   !IS_FC: A = hmid[ebase+row] contiguous, out = atomicAdd(gate * acc)
template<int KD, int ND, int TN, int NCTP, bool IS_FC>
__global__ __launch_bounds__(256) void moe_gemm(
    const unsigned short* __restrict__ Asrc,
    const unsigned short* __restrict__ Bsrc,    // [E][ND][KD] (B^T form)
    const int* __restrict__ counts,
    const int* __restrict__ entries,
    const float* __restrict__ gates,
    unsigned short* __restrict__ hmid,
    float* __restrict__ outp)
{
    constexpr int AJ = TN / 32;        // col frags per wave (4 or 2)
    constexpr int CB = TN / 32;        // B staging calls per thread (4 or 2)
    int bkt  = blockIdx.x & 7;         // bucket == expert
    int slot = blockIdx.x >> 3;        // 0..SLOTS-1

    // per-expert geometry from the 8 routing counters (uniform scalar work)
    int cs[NEXP];
#pragma unroll
    for (int e = 0; e < NEXP; e++) cs[e] = counts[e];
    int n_e = cs[bkt];
    int rts = (n_e + 127) >> 7;
    int nfill = rts * NCTP;
    if (slot >= nfill) return;
    int ebase = 0;
#pragma unroll
    for (int e = 0; e < NEXP; e++) if (e < bkt) ebase += cs[e];
    const int* lst = entries + bkt * TOKENS;

    int tid = threadIdx.x;
    int w = tid >> 6;          // wave 0..3
    int l = tid & 63;          // lane
    int sg = l & 7;
    int lr8 = l >> 3;          // row-within-8 staged by this lane
    int lo = l & 15;
    int q  = l >> 4;
    int wr = w >> 1, wc = w & 1;

    __shared__ __align__(16) unsigned short sA[128 * 64];
    __shared__ __align__(16) unsigned short sB[TN * 64];

    // fragment LDS offsets (item-independent)
    int aOff[4][2], bOff[AJ][2];
#pragma unroll
    for (int i = 0; i < 4; i++) {
        int m = wr * 64 + i * 16 + lo;
#pragma unroll
        for (int s = 0; s < 2; s++)
            aOff[i][s] = m * 64 + ((s * 4 + q) ^ (m & 7)) * 8;
    }
#pragma unroll
    for (int j = 0; j < AJ; j++) {
        int n = wc * (TN / 2) + j * 16 + lo;
#pragma unroll
        for (int s = 0; s < 2; s++)
            bOff[j][s] = n * 64 + ((s * 4 + q) ^ (n & 7)) * 8;
    }

    for (int p = slot; p < nfill; p += SLOTS) {   // backstop stride; 1 iter typical
        int ct   = p / rts;
        int r    = p - ct * rts;
        int row0 = r << 7;
        int n0 = ct * TN;

        // ---- staging addresses: rows are 128B (64 shorts), 8 segs of 16B.
        // A call covers 8 rows (64 lanes x 16B = 1KB). Global K-seg for
        // (row r, LDS seg sg) is sg ^ (r&7). Wave w stages A rows
        // [w*32, w*32+32) (4 calls) and B rows [w*(TN/4), ...) (CB calls).
        const unsigned short* Ag[4];
        int aLds[4];
#pragma unroll
        for (int c = 0; c < 4; c++) {
            int rr = w * 32 + c * 8 + lr8;       // tile row
            int gr = row0 + rr;
            int id = gr < n_e ? gr : n_e - 1;    // clamp (discarded in epilogue)
            size_t arow = IS_FC ? (size_t)(lst[id] >> 1) : (size_t)(ebase + id);
            Ag[c] = Asrc + arow * KD + (size_t)((sg ^ (rr & 7)) * 8);
            aLds[c] = (w * 32 + c * 8) * 64;     // wave-uniform chunk base
        }
        const unsigned short* Bg[CB];
        int bLds[CB];
#pragma unroll
        for (int c = 0; c < CB; c++) {
            int rr = w * (TN / 4) + c * 8 + lr8;
            Bg[c] = Bsrc + ((size_t)bkt * ND + n0 + rr) * KD + (size_t)((sg ^ (rr & 7)) * 8);
            bLds[c] = (w * (TN / 4) + c * 8) * 64;
        }

        f32x4 acc[4][AJ];
#pragma unroll
        for (int i = 0; i < 4; i++)
#pragma unroll
            for (int j = 0; j < AJ; j++) acc[i][j] = (f32x4){0.f, 0.f, 0.f, 0.f};

        for (int k0 = 0; k0 < KD; k0 += 64) {
#pragma unroll
            for (int c = 0; c < 4; c++) gload_lds16(Ag[c] + k0, sA + aLds[c]);
#pragma unroll
            for (int c = 0; c < CB; c++) gload_lds16(Bg[c] + k0, sB + bLds[c]);
            __syncthreads();                    // drains vmcnt (compiler-inserted)
#pragma unroll
            for (int s = 0; s < 2; s++) {
                bf16x8 a[4], b[AJ];
#pragma unroll
                for (int i = 0; i < 4; i++) a[i] = *(const bf16x8*)(sA + aOff[i][s]);
#pragma unroll
                for (int j = 0; j < AJ; j++) b[j] = *(const bf16x8*)(sB + bOff[j][s]);
#pragma unroll
                for (int i = 0; i < 4; i++)
#pragma unroll
                    for (int j = 0; j < AJ; j++)
                        acc[i][j] = __builtin_amdgcn_mfma_f32_16x16x32_bf16(a[i], b[j], acc[i][j], 0, 0, 0);
            }
            __syncthreads();                    // protect LDS before next staging
        }

        // ---- epilogue (D: col=lo, row=q*4+rr)
#pragma unroll
        for (int i = 0; i < 4; i++) {
            int rowB = row0 + wr * 64 + i * 16 + q * 4;
#pragma unroll
            for (int rr = 0; rr < 4; rr++) {
                int orow = rowB + rr;
                if (orow < n_e) {
                    if (IS_FC) {
                        size_t hrow = (size_t)(ebase + orow);
#pragma unroll
                        for (int j = 0; j < AJ; j++) {
                            float v = acc[i][j][rr];
                            v = 0.5f * v * (1.f + erff(v * 0.70710678118654752f));  // exact gelu
                            hmid[hrow * ND + n0 + wc * (TN / 2) + j * 16 + lo] = f2bf(v);
                        }
                    } else {
                        int token = lst[orow] >> 1;
                        float g = gates[bkt * TOKENS + orow];
#pragma unroll
                        for (int j = 0; j < AJ; j++) {
                            atomicAdd(&outp[(size_t)token * ND + n0 + wc * (TN / 2) + j * 16 + lo],
                                      acc[i][j][rr] * g);
                        }
                    }
                }
            }
        }
    }
}

// ---------------------------------------------------------------------------
extern "C" void kernel_launch(void* const* d_in, const int* in_sizes, int n_in,
                              void* d_out, int out_size, void* d_ws, size_t ws_size,
                              hipStream_t stream) {
    const float* x     = (const float*)d_in[0];   // [T, H]
    const float* gw    = (const float*)d_in[1];   // [E, H]
    const float* wfc   = (const float*)d_in[2];   // [E, FF, H]
    const float* wproj = (const float*)d_in[3];   // [E, H, FF]
    float* outp   = (float*)d_out;                       // [T*H]
    float* logits = outp + (size_t)TOKENS * HDIM;        // [T*E]

    char* ws = (char*)d_ws;
    int*   counts  = (int*)ws;                            // 8 ints
    size_t off = 256;
    int*   entries = (int*)(ws + off);                    // [E][T]
    float* gates   = (float*)(ws + off + NEXP * TOKENS * 4);
    off += 2ull * NEXP * TOKENS * 4;
    int*   tok_e   = (int*)(ws + off);   off += (size_t)TOKENS * 2 * 4;
    float* tok_g   = (float*)(ws + off); off += (size_t)TOKENS * 2 * 4;
    unsigned short* x_bf   = (unsigned short*)(ws + off); off += (size_t)TOKENS * HDIM * 2;
    unsigned short* wfc_bf = (unsigned short*)(ws + off); off += (size_t)NEXP * FFDIM * HDIM * 2;
    unsigned short* wpj_bf = (unsigned short*)(ws + off); off += (size_t)NEXP * HDIM * FFDIM * 2;
    unsigned short* hmid   = (unsigned short*)(ws + off);        // [2T][FF] bf16, slot-compacted

    cast_bf16_2<<<2048, 256, 0, stream>>>(wfc, wfc_bf, wproj, wpj_bf,
                                          NEXP * FFDIM * HDIM / 4);
    gating<<<TOKENS / 4, 256, 0, stream>>>(x, gw, logits, tok_e, tok_g, x_bf, outp);
    build_lists<<<1, 1024, 0, stream>>>(tok_e, tok_g, counts, entries, gates);
    moe_gemm<HDIM, FFDIM, 128, FFDIM / 128, true ><<<GEMM_GRID, 256, 0, stream>>>(
        x_bf, wfc_bf, counts, entries, gates, hmid, outp);
    moe_gemm<FFDIM, HDIM, 64, HDIM / 64, false><<<GEMM_GRID, 256, 0, stream>>>(
        hmid, wpj_bf, counts, entries, gates, hmid, outp);
}

// Round 5
// 222.955 us; speedup vs baseline: 1.4567x; 1.0509x over previous
//
#include <hip/hip_runtime.h>
#include <hip/hip_bf16.h>
#include <math.h>
#include <stdint.h>

// Problem constants (B=2, S=2048 -> T=4096 tokens)
#define TOKENS 4096
#define HDIM   768
#define FFDIM  1536
#define NEXP   8
#define GEMM_GRID 1024  // 128 slots per bucket; id%8 = bucket -> XCD affinity
#define SLOTS (GEMM_GRID / 8)

typedef __attribute__((ext_vector_type(8))) short bf16x8;   // 8 bf16 = 4 VGPRs
typedef __attribute__((ext_vector_type(4))) float f32x4;    // MFMA accumulator

// round-to-nearest-even f32 -> bf16 (bit pattern)
__device__ __forceinline__ unsigned short f2bf(float f) {
    union { float f; uint32_t u; } c; c.f = f;
    uint32_t u = c.u;
    uint32_t r = (u + 0x7FFFu + ((u >> 16) & 1u)) >> 16;
    return (unsigned short)r;
}

// async global->LDS, 16B per lane; LDS dest is wave-uniform base + lane*16
__device__ __forceinline__ void gload_lds16(const void* g, void* l) {
    __builtin_amdgcn_global_load_lds(
        (const __attribute__((address_space(1))) void*)g,
        (__attribute__((address_space(3))) void*)l, 16, 0, 0);
}

// ---------------------------------------------------------------------------
// both weight casts in one dispatch; n4 = float4 count of EACH tensor
__global__ void cast_bf16_2(const float* __restrict__ s1, unsigned short* __restrict__ d1,
                            const float* __restrict__ s2, unsigned short* __restrict__ d2,
                            int n4) {
    int stride = gridDim.x * blockDim.x;
    for (int i = blockIdx.x * blockDim.x + threadIdx.x; i < 2 * n4; i += stride) {
        const float4* s = (i < n4) ? (const float4*)s1 : (const float4*)s2;
        ushort4* d = (i < n4) ? (ushort4*)d1 : (ushort4*)d2;
        int j = (i < n4) ? i : i - n4;
        float4 v = s[j];
        ushort4 o;
        o.x = f2bf(v.x); o.y = f2bf(v.y); o.z = f2bf(v.z); o.w = f2bf(v.w);
        d[j] = o;
    }
}

// ---------------------------------------------------------------------------
// Gating: one wave per token (4 tokens / 256-thread block). fp32 logits
// (checked output!), top-2 softmax, NO atomics (r2: contended atomics are a
// latency chain, 102 us). Fused: bf16 cast of x, zeroing of outp.
__global__ __launch_bounds__(256) void gating(
    const float* __restrict__ x, const float* __restrict__ gw,
    float* __restrict__ logits,
    int* __restrict__ tok_e, float* __restrict__ tok_g,
    unsigned short* __restrict__ x_bf, float* __restrict__ outp)
{
    // zero outp: 786432 float4 over 1024 blocks = 3 per thread
    float4 zz = make_float4(0.f, 0.f, 0.f, 0.f);
#pragma unroll
    for (int j = 0; j < 3; j++)
        ((float4*)outp)[blockIdx.x * 768 + j * 256 + threadIdx.x] = zz;

    int t = blockIdx.x * 4 + (threadIdx.x >> 6);
    int lane = threadIdx.x & 63;
    const float4* xt = (const float4*)(x + (size_t)t * HDIM);   // 192 float4/token
    const float4* gw4 = (const float4*)gw;                      // [E][192]
    ushort4* xbt = (ushort4*)(x_bf + (size_t)t * HDIM);
    float acc[NEXP];
#pragma unroll
    for (int e = 0; e < NEXP; e++) acc[e] = 0.f;
#pragma unroll
    for (int it = 0; it < 3; it++) {
        int i = lane + it * 64;
        float4 xv = xt[i];
        ushort4 o;
        o.x = f2bf(xv.x); o.y = f2bf(xv.y); o.z = f2bf(xv.z); o.w = f2bf(xv.w);
        xbt[i] = o;
#pragma unroll
        for (int e = 0; e < NEXP; e++) {
            float4 wv = gw4[e * 192 + i];
            acc[e] += xv.x * wv.x + xv.y * wv.y + xv.z * wv.z + xv.w * wv.w;
        }
    }
#pragma unroll
    for (int e = 0; e < NEXP; e++) {
#pragma unroll
        for (int off = 32; off > 0; off >>= 1)
            acc[e] += __shfl_xor(acc[e], off);
    }
    if (lane == 0) {
        float4 l0 = make_float4(acc[0], acc[1], acc[2], acc[3]);
        float4 l1 = make_float4(acc[4], acc[5], acc[6], acc[7]);
        float4* lp = (float4*)(logits + (size_t)t * NEXP);
        lp[0] = l0; lp[1] = l1;
        int i0 = 0; float v0 = acc[0];
#pragma unroll
        for (int e = 1; e < NEXP; e++) if (acc[e] > v0) { v0 = acc[e]; i0 = e; }
        int i1 = -1; float v1 = -3.4e38f;
#pragma unroll
        for (int e = 0; e < NEXP; e++) if (e != i0 && acc[e] > v1) { v1 = acc[e]; i1 = e; }
        float g0 = 1.f / (1.f + expf(v1 - v0));   // softmax over top-2 (v0 >= v1)
        tok_e[t * 2] = i0; tok_e[t * 2 + 1] = i1;
        tok_g[t * 2] = g0; tok_g[t * 2 + 1] = 1.f - g0;
    }
}

// ---------------------------------------------------------------------------
// Build per-expert routed lists deterministically (no global atomics).
// Single block, 1024 threads (16 waves), 8 (token,k) entries per thread.
// Per-wave __shfl_up u64 scan + 16-wave fixup. GEMMs derive geometry from
// counts[8].
__global__ __launch_bounds__(1024) void build_lists(
    const int* __restrict__ tok_e, const float* __restrict__ tok_g,
    int* __restrict__ counts,
    int* __restrict__ entries, float* __restrict__ gates)
{
    __shared__ unsigned long long wlo[16], whi[16];
    int tid = threadIdx.x;
    int lane = tid & 63, wid = tid >> 6;

    int eL[8]; float gL[8];
    int4 ea = ((const int4*)tok_e)[tid * 2];
    int4 eb = ((const int4*)tok_e)[tid * 2 + 1];
    float4 ga = ((const float4*)tok_g)[tid * 2];
    float4 gb = ((const float4*)tok_g)[tid * 2 + 1];
    eL[0] = ea.x; eL[1] = ea.y; eL[2] = ea.z; eL[3] = ea.w;
    eL[4] = eb.x; eL[5] = eb.y; eL[6] = eb.z; eL[7] = eb.w;
    gL[0] = ga.x; gL[1] = ga.y; gL[2] = ga.z; gL[3] = ga.w;
    gL[4] = gb.x; gL[5] = gb.y; gL[6] = gb.z; gL[7] = gb.w;

    unsigned long long clo = 0, chi = 0;
#pragma unroll
    for (int j = 0; j < 8; j++) {
        int e = eL[j];
        unsigned long long one = 1ull << ((e & 3) * 16);
        if (e < 4) clo += one; else chi += one;
    }
    unsigned long long ilo = clo, ihi = chi;
#pragma unroll
    for (int s = 1; s < 64; s <<= 1) {
        unsigned long long t1 = __shfl_up(ilo, s);
        unsigned long long t2 = __shfl_up(ihi, s);
        if (lane >= s) { ilo += t1; ihi += t2; }
    }
    if (lane == 63) { wlo[wid] = ilo; whi[wid] = ihi; }
    __syncthreads();
    if (tid == 0) {
        unsigned long long rl = 0, rh = 0;
#pragma unroll
        for (int i = 0; i < 16; i++) {
            unsigned long long a = wlo[i], b = whi[i];
            wlo[i] = rl; whi[i] = rh;   // exclusive wave prefix
            rl += a; rh += b;
        }
#pragma unroll
        for (int e = 0; e < 4; e++) {
            counts[e]     = (int)((rl >> (e * 16)) & 0xFFFF);
            counts[e + 4] = (int)((rh >> (e * 16)) & 0xFFFF);
        }
    }
    __syncthreads();
    unsigned long long rlo = wlo[wid] + (ilo - clo);   // exclusive thread prefix
    unsigned long long rhi = whi[wid] + (ihi - chi);
#pragma unroll
    for (int j = 0; j < 8; j++) {
        int e = eL[j];
        int sh = (e & 3) * 16;
        unsigned long long one = 1ull << sh;
        int slot;
        if (e < 4) { slot = (int)((rlo >> sh) & 0xFFFF); rlo += one; }
        else       { slot = (int)((rhi >> sh) & 0xFFFF); rhi += one; }
        entries[e * TOKENS + slot] = tid * 8 + j;   // = t*2+k
        gates[e * TOKENS + slot]   = gL[j];
    }
}

// ---------------------------------------------------------------------------
// Routed GEMM, r5: BM=256 tiles, 8 waves (512 thr) in a 4x2 wave grid.
// A/B EXPERIMENT (two mechanisms, one per dispatch — counters attribute):
//   DBUF=false (GEMM1): single-buffer 2-barrier __syncthreads K-loop
//     (drain-0 control). LDS 48KB -> 3 blk/CU; ~425 items all resident.
//   DBUF=true  (GEMM2): T4 counted-vmcnt double-buffer: raw s_barrier +
//     s_waitcnt vmcnt(NV) (never 0 in-loop) keeps the next K-step's
//     global_load_lds in flight ACROSS the barriers and the MFMA cluster.
//     r4 analysis: ~6500 cyc/K-step with all blocks in lockstep at the
//     drain-0 barrier; per m218 counted-vs-drain0 is the lever (+38-73%),
//     r1 failed because __syncthreads implies vmcnt(0). LDS 80KB -> 2
//     blk/CU (capacity 512 >= ~425 items, single span). setprio(1) around
//     MFMA (role diversity exists once loads span phases).
// WAR safety: a buffer staged at phase t was last READ at phase t-1 with
// TWO raw barriers in between (stricter than the verified T3 minimum
// template). vmcnt counts only this wave's vmem ops; ds_read->MFMA waits
// are compiler-inserted lgkmcnt (no inline-asm ds_read -> rule 18 n/a).
// Leftover epilogue atomics only make vmcnt(NV) conservative (safe).
// LDS rows 128B (8x16B segs), XOR swizzle seg^(row&7): 0 bank conflicts
// (verified r6). Geometry from counts[8]: rts=ceil(c/256), nfill=rts*NCTP,
// bucket == expert (XCD-affine under round-robin dispatch).
template<int KD, int ND, int TN, int NCTP, bool IS_FC, bool DBUF>
__global__ __launch_bounds__(512) void moe_gemm(
    const unsigned short* __restrict__ Asrc,
    const unsigned short* __restrict__ Bsrc,    // [E][ND][KD] (B^T form)
    const int* __restrict__ counts,
    const int* __restrict__ entries,
    const float* __restrict__ gates,
    unsigned short* __restrict__ hmid,
    float* __restrict__ outp)
{
    constexpr int BM = 256;
    constexpr int AJ = TN / 32;        // col frags per wave (4 or 2)
    constexpr int CB = TN / 64;        // B staging calls per wave (2 or 1)
    constexpr int NV = 4 + CB;         // gload_lds per wave per stage
    int bkt  = blockIdx.x & 7;         // bucket == expert
    int slot = blockIdx.x >> 3;        // 0..SLOTS-1

    // per-expert geometry from the 8 routing counters (uniform scalar work)
    int cs[NEXP];
#pragma unroll
    for (int e = 0; e < NEXP; e++) cs[e] = counts[e];
    int n_e = cs[bkt];
    int rts = (n_e + BM - 1) >> 8;
    int nfill = rts * NCTP;
    if (slot >= nfill) return;
    int ebase = 0;
#pragma unroll
    for (int e = 0; e < NEXP; e++) if (e < bkt) ebase += cs[e];
    const int* lst = entries + bkt * TOKENS;

    int tid = threadIdx.x;
    int w = tid >> 6;          // wave 0..7
    int l = tid & 63;          // lane
    int sg = l & 7;
    int lr8 = l >> 3;          // row-within-8 staged by this lane
    int lo = l & 15;
    int q  = l >> 4;
    int wr = w >> 1, wc = w & 1;   // 4x2 wave grid: 64 rows x TN/2 cols each

    __shared__ __align__(16) unsigned short sA[(DBUF ? 2 : 1) * BM * 64];
    __shared__ __align__(16) unsigned short sB[(DBUF ? 2 : 1) * TN * 64];
    unsigned short* sA0 = sA;
    unsigned short* sA1 = sA + BM * 64;   // compile-time offset (static alias)
    unsigned short* sB0 = sB;
    unsigned short* sB1 = sB + TN * 64;

    // fragment LDS offsets (item-independent)
    int aOff[4][2], bOff[AJ][2];
#pragma unroll
    for (int i = 0; i < 4; i++) {
        int m = wr * 64 + i * 16 + lo;
#pragma unroll
        for (int s = 0; s < 2; s++)
            aOff[i][s] = m * 64 + ((s * 4 + q) ^ (m & 7)) * 8;
    }
#pragma unroll
    for (int j = 0; j < AJ; j++) {
        int n = wc * (TN / 2) + j * 16 + lo;
#pragma unroll
        for (int s = 0; s < 2; s++)
            bOff[j][s] = n * 64 + ((s * 4 + q) ^ (n & 7)) * 8;
    }

    for (int p = slot; p < nfill; p += SLOTS) {   // backstop stride; 1 iter typical
        int ct   = p / rts;
        int r    = p - ct * rts;
        int row0 = r << 8;
        int n0 = ct * TN;

        // ---- staging addresses: rows are 128B (64 shorts), 8 segs of 16B.
        // A call covers 8 rows (64 lanes x 16B = 1KB). Global K-seg for
        // (row rr, LDS seg sg) is sg ^ (rr&7). Wave w stages A rows
        // [w*32, w*32+32) (4 calls) and B rows [w*(TN/8)*?, ...) (CB calls).
        const unsigned short* Ag[4];
        int aLds[4];
#pragma unroll
        for (int c = 0; c < 4; c++) {
            int rr = w * 32 + c * 8 + lr8;       // tile row 0..255
            int gr = row0 + rr;
            int id = gr < n_e ? gr : n_e - 1;    // clamp (discarded in epilogue)
            size_t arow = IS_FC ? (size_t)(lst[id] >> 1) : (size_t)(ebase + id);
            Ag[c] = Asrc + arow * KD + (size_t)((sg ^ (rr & 7)) * 8);
            aLds[c] = (w * 32 + c * 8) * 64;     // wave-uniform chunk base
        }
        const unsigned short* Bg[CB];
        int bLds[CB];
#pragma unroll
        for (int c = 0; c < CB; c++) {
            int rr = w * (TN / 8) + c * 8 + lr8; // tile row 0..TN-1
            Bg[c] = Bsrc + ((size_t)bkt * ND + n0 + rr) * KD + (size_t)((sg ^ (rr & 7)) * 8);
            bLds[c] = (w * (TN / 8) + c * 8) * 64;
        }

        f32x4 acc[4][AJ];
#pragma unroll
        for (int i = 0; i < 4; i++)
#pragma unroll
            for (int j = 0; j < AJ; j++) acc[i][j] = (f32x4){0.f, 0.f, 0.f, 0.f};

        auto stage = [&](unsigned short* SA, unsigned short* SB, int k0) {
#pragma unroll
            for (int c = 0; c < 4; c++) gload_lds16(Ag[c] + k0, SA + aLds[c]);
#pragma unroll
            for (int c = 0; c < CB; c++) gload_lds16(Bg[c] + k0, SB + bLds[c]);
        };
        auto compute = [&](const unsigned short* SA, const unsigned short* SB) {
#pragma unroll
            for (int s = 0; s < 2; s++) {
                bf16x8 a[4], b[AJ];
#pragma unroll
                for (int i = 0; i < 4; i++) a[i] = *(const bf16x8*)(SA + aOff[i][s]);
#pragma unroll
                for (int j = 0; j < AJ; j++) b[j] = *(const bf16x8*)(SB + bOff[j][s]);
#pragma unroll
                for (int i = 0; i < 4; i++)
#pragma unroll
                    for (int j = 0; j < AJ; j++)
                        acc[i][j] = __builtin_amdgcn_mfma_f32_16x16x32_bf16(a[i], b[j], acc[i][j], 0, 0, 0);
            }
        };

        if constexpr (!DBUF) {
            // control arm: single-buffer, drain-0 __syncthreads loop (r4)
            for (int k0 = 0; k0 < KD; k0 += 64) {
                stage(sA0, sB0, k0);
                __syncthreads();                // drains vmcnt (compiler-inserted)
                compute(sA0, sB0);
                __syncthreads();                // protect LDS before next staging
            }
        } else {
            // T4 arm: counted-vmcnt double-buffer, raw barriers.
            // outstanding after each stage issue = 2*NV; vmcnt(NV) retires the
            // older buffer's loads while the newest NV stay in flight.
#define WAITN asm volatile("s_waitcnt vmcnt(%0)" :: "n"(NV) : "memory")
#define WAIT0 asm volatile("s_waitcnt vmcnt(0)" ::: "memory")
            stage(sA0, sB0, 0);
            for (int k0 = 0; k0 < KD; k0 += 128) {   // KD/64 even for both GEMMs
                stage(sA1, sB1, k0 + 64);            // always valid (k0+64 < KD)
                WAITN;
                __builtin_amdgcn_s_barrier();
                __builtin_amdgcn_s_setprio(1);
                compute(sA0, sB0);
                __builtin_amdgcn_s_setprio(0);
                __builtin_amdgcn_s_barrier();
                if (k0 + 128 < KD) {
                    stage(sA0, sB0, k0 + 128);
                    WAITN;
                } else {
                    WAIT0;
                }
                __builtin_amdgcn_s_barrier();
                __builtin_amdgcn_s_setprio(1);
                compute(sA1, sB1);
                __builtin_amdgcn_s_setprio(0);
                __builtin_amdgcn_s_barrier();
            }
#undef WAITN
#undef WAIT0
        }

        // ---- epilogue (D: col=lo, row=q*4+rr)
#pragma unroll
        for (int i = 0; i < 4; i++) {
            int rowB = row0 + wr * 64 + i * 16 + q * 4;
#pragma unroll
            for (int rr = 0; rr < 4; rr++) {
                int orow = rowB + rr;
                if (orow < n_e) {
                    if (IS_FC) {
                        size_t hrow = (size_t)(ebase + orow);
#pragma unroll
                        for (int j = 0; j < AJ; j++) {
                            float v = acc[i][j][rr];
                            v = 0.5f * v * (1.f + erff(v * 0.70710678118654752f));  // exact gelu
                            hmid[hrow * ND + n0 + wc * (TN / 2) + j * 16 + lo] = f2bf(v);
                        }
                    } else {
                        int token = lst[orow] >> 1;
                        float g = gates[bkt * TOKENS + orow];
#pragma unroll
                        for (int j = 0; j < AJ; j++) {
                            atomicAdd(&outp[(size_t)token * ND + n0 + wc * (TN / 2) + j * 16 + lo],
                                      acc[i][j][rr] * g);
                        }
                    }
                }
            }
        }
    }
}

// ---------------------------------------------------------------------------
extern "C" void kernel_launch(void* const* d_in, const int* in_sizes, int n_in,
                              void* d_out, int out_size, void* d_ws, size_t ws_size,
                              hipStream_t stream) {
    const float* x     = (const float*)d_in[0];   // [T, H]
    const float* gw    = (const float*)d_in[1];   // [E, H]
    const float* wfc   = (const float*)d_in[2];   // [E, FF, H]
    const float* wproj = (const float*)d_in[3];   // [E, H, FF]
    float* outp   = (float*)d_out;                       // [T*H]
    float* logits = outp + (size_t)TOKENS * HDIM;        // [T*E]

    char* ws = (char*)d_ws;
    int*   counts  = (int*)ws;                            // 8 ints
    size_t off = 256;
    int*   entries = (int*)(ws + off);                    // [E][T]
    float* gates   = (float*)(ws + off + NEXP * TOKENS * 4);
    off += 2ull * NEXP * TOKENS * 4;
    int*   tok_e   = (int*)(ws + off);   off += (size_t)TOKENS * 2 * 4;
    float* tok_g   = (float*)(ws + off); off += (size_t)TOKENS * 2 * 4;
    unsigned short* x_bf   = (unsigned short*)(ws + off); off += (size_t)TOKENS * HDIM * 2;
    unsigned short* wfc_bf = (unsigned short*)(ws + off); off += (size_t)NEXP * FFDIM * HDIM * 2;
    unsigned short* wpj_bf = (unsigned short*)(ws + off); off += (size_t)NEXP * HDIM * FFDIM * 2;
    unsigned short* hmid   = (unsigned short*)(ws + off);        // [2T][FF] bf16, slot-compacted

    cast_bf16_2<<<2048, 256, 0, stream>>>(wfc, wfc_bf, wproj, wpj_bf,
                                          NEXP * FFDIM * HDIM / 4);
    gating<<<TOKENS / 4, 256, 0, stream>>>(x, gw, logits, tok_e, tok_g, x_bf, outp);
    build_lists<<<1, 1024, 0, stream>>>(tok_e, tok_g, counts, entries, gates);
    moe_gemm<HDIM, FFDIM, 128, FFDIM / 128, true,  false><<<GEMM_GRID, 512, 0, stream>>>(
        x_bf, wfc_bf, counts, entries, gates, hmid, outp);
    moe_gemm<FFDIM, HDIM, 64,  HDIM / 64,   false, true ><<<GEMM_GRID, 512, 0, stream>>>(
        hmid, wpj_bf, counts, entries, gates, hmid, outp);
}